// Round 1
// baseline (2143.774 us; speedup 1.0000x reference)
//
#include <hip/hip_runtime.h>

#define D 129
#define DK 128
#define N1 8193
#define NN 8192
#define INV_N (1.0f/8192.0f)
#define VROWS 144
#define VS 8200
#define ZS 8200
#define LSTR 136
#define SL 256

typedef __attribute__((ext_vector_type(8))) short bf16x8;
typedef __attribute__((ext_vector_type(4))) short bf16x4;
typedef __attribute__((ext_vector_type(4))) float f32x4;

__device__ __forceinline__ short f2bf(float x){
  unsigned u = __float_as_uint(x);
  unsigned r = (u + 0x7fffu + ((u>>16)&1u)) >> 16;
  return (short)r;
}

// swizzled LDS offset (elements): row stride 136 bf16 (272B, 16B-aligned rows),
// 8-col blocks XOR'd with row bits -> 2-way-max conflicts on b128 frag reads
__device__ __forceinline__ int swz(int row, int kb){
  return row*LSTR + ((kb ^ ((row>>3)&7))<<3);
}

__global__ void k_cast(const float* __restrict__ Z, short* __restrict__ Zbf){
  int total = DK*ZS;
  for(int idx = blockIdx.x*256+threadIdx.x; idx<total; idx += gridDim.x*256){
    int d = idx/ZS, t = idx - d*ZS;
    Zbf[idx] = (t<N1) ? f2bf(Z[d*N1+t]) : (short)0;
  }
}

// Y = Q@Z, PZ = P@Z (K=129, fp32), plus bf16 cast of Y rows 0..127
__global__ void k_small(const float* __restrict__ Z, const float* __restrict__ P,
                        const float* __restrict__ Q, float* __restrict__ Y,
                        short* __restrict__ Ybf, float* __restrict__ PZ){
  __shared__ float qs[8][D], ps[8][D];
  int r0 = blockIdx.y*8;
  for(int i=threadIdx.x;i<8*D;i+=256){
    int rr=i/D, cc=i-rr*D;
    float qv=0.f, pv=0.f;
    if(r0+rr<D){ qv=Q[(r0+rr)*D+cc]; pv=P[(r0+rr)*D+cc]; }
    qs[rr][cc]=qv; ps[rr][cc]=pv;
  }
  __syncthreads();
  int t = blockIdx.x*256+threadIdx.x;
  if(t>=N1) return;
  float ay[8], ap[8];
  #pragma unroll
  for(int rr=0;rr<8;rr++){ ay[rr]=0.f; ap[rr]=0.f; }
  for(int k=0;k<D;k++){
    float z = Z[k*N1+t];
    #pragma unroll
    for(int rr=0;rr<8;rr++){ ay[rr]=fmaf(qs[rr][k],z,ay[rr]); ap[rr]=fmaf(ps[rr][k],z,ap[rr]); }
  }
  #pragma unroll
  for(int rr=0;rr<8;rr++){
    int r=r0+rr;
    if(r<D){
      Y[r*N1+t]=ay[rr];
      PZ[r*N1+t]=ap[rr];
      if(r<DK) Ybf[(size_t)r*ZS+t]=f2bf(ay[rr]);
    }
  }
}

// W[d,j] = sum_{k=0..SL-1} PZ[d,j+k]*0.9^k  (truncated suffix scan; 0.9^256~2e-12)
__global__ void k_scan(const float* __restrict__ PZ, float* __restrict__ W){
  __shared__ float s[256+SL];
  int d = blockIdx.y;
  int j0 = blockIdx.x*256;
  for(int i=threadIdx.x;i<256+SL;i+=256){
    int j=j0+i;
    s[i]=(j<NN)? PZ[d*N1+j] : 0.f;   // source index i<=n-1 only (last row of M is zero)
  }
  __syncthreads();
  int t=threadIdx.x;
  int j=j0+t;
  if(j>=N1) return;
  float w=0.f, f=1.f;
  #pragma unroll 4
  for(int k=0;k<SL;k++){ w = fmaf(f, s[t+k], w); f *= 0.9f; }
  W[d*N1+j]=w;
}

// V[d,i] = W[d,i]/S[i] in bf16, padded to 144 rows x stride 8200
__global__ void k_v(const float* __restrict__ W, const float* __restrict__ S,
                    short* __restrict__ V){
  int total=VROWS*VS;
  for(int idx=blockIdx.x*256+threadIdx.x; idx<total; idx+=gridDim.x*256){
    int dd=idx/VS, ii=idx-dd*VS;
    float v=0.f;
    if(dd<D && ii<NN) v = W[dd*N1+ii]/S[ii];  // col 8192: W=0 -> V=0 (avoid 0/0)
    V[idx]=f2bf(v);
  }
}

// stage a 128(k) x COLS(c) bf16 tile transposed into lds[c][k] (swizzled)
template<int COLS>
__device__ __forceinline__ void stage_T(const short* __restrict__ src, int c0, short* lds){
  const int CB = COLS/8;
  int tid = threadIdx.x;
  if(tid < 16*CB){
    int kb = tid/CB, cb = tid - kb*CB;
    const short* p = src + (size_t)(kb*8)*ZS + c0 + cb*8;
    short v[8][8];
    if(c0+cb*8+8 <= N1){
      #pragma unroll
      for(int s=0;s<8;s++){
        bf16x8 tv = *(const bf16x8*)(p + (size_t)s*ZS);
        #pragma unroll
        for(int u=0;u<8;u++) v[s][u]=tv[u];
      }
    } else {
      #pragma unroll
      for(int s=0;s<8;s++){
        #pragma unroll
        for(int u=0;u<8;u++){
          int c=c0+cb*8+u;
          v[s][u]=(c<N1)? p[(size_t)s*ZS+u] : (short)0;
        }
      }
    }
    #pragma unroll
    for(int u=0;u<8;u++){
      bf16x8 o;
      #pragma unroll
      for(int s=0;s<8;s++) o[s]=v[s][u];
      *(bf16x8*)(lds + swz(cb*8+u, kb)) = o;
    }
  }
}

// PASS 0: S[i] += sum_j exp(X[i,j]) over this block's j-strip (X^T orientation, M=j)
// PASS 1: Zn[d,j] += INV_N * sum_i V[d,i]*exp(X[i,j])   (X orientation, then V@E)
template<int PASS>
__global__ __launch_bounds__(256) void k_attn(
    const short* __restrict__ Zbf, const short* __restrict__ Ybf,
    const float* __restrict__ Zc, const float* __restrict__ Yf,
    float* __restrict__ S, const short* __restrict__ Vbf, float* __restrict__ Zn){
  __shared__ short ldsY[64*LSTR];
  __shared__ short ldsZ[128*LSTR];
  __shared__ float y128s[64];
  __shared__ float z128s[128];

  const int tid=threadIdx.x;
  const int w=tid>>6, l=tid&63, g=l>>4, lm=l&15;
  const int j0=blockIdx.x*64;

  stage_T<64>(Ybf, j0, ldsY);
  if(tid<64){ int jj=j0+tid; y128s[tid] = (jj<N1)? Yf[(size_t)DK*N1+jj] : 0.f; }

  const f32x4 z4 = {0.f,0.f,0.f,0.f};
  f32x4 acc2[9];
  if constexpr(PASS==1){
    #pragma unroll
    for(int m=0;m<9;m++) acc2[m]=z4;
  }
  const bool jvalid = (j0 + w*16 + lm) < N1;

  for(int it=0; it<8; it++){
    int i0 = blockIdx.y*1024 + it*128;
    __syncthreads();                       // protect LDS from previous iteration's readers
    stage_T<128>(Zbf, i0, ldsZ);
    if(tid<128) z128s[tid] = Zc[(size_t)DK*N1 + i0 + tid];
    __syncthreads();

    if constexpr(PASS==0){
      f32x4 acc[8];
      #pragma unroll
      for(int ib=0;ib<8;ib++) acc[ib]=z4;
      #pragma unroll
      for(int kk=0;kk<4;kk++){
        bf16x8 a = *(const bf16x8*)(ldsY + swz(w*16+lm, kk*4+g));
        #pragma unroll
        for(int ib=0;ib<8;ib++){
          bf16x8 b = *(const bf16x8*)(ldsZ + swz(ib*16+lm, kk*4+g));
          acc[ib] = __builtin_amdgcn_mfma_f32_16x16x32_bf16(a,b,acc[ib],0,0,0);
        }
      }
      #pragma unroll
      for(int ib=0;ib<8;ib++){
        float psum=0.f;
        #pragma unroll
        for(int r=0;r<4;r++){
          int jl = w*16 + 4*g + r;
          float x = acc[ib][r] + z128s[ib*16+lm]*y128s[jl];
          if(j0+jl < N1) psum += __expf(x);
        }
        psum += __shfl_xor(psum, 16);
        psum += __shfl_xor(psum, 32);
        if(g==0) atomicAdd(&S[i0+ib*16+lm], psum);
      }
    } else {
      f32x4 acc1[8];
      #pragma unroll
      for(int mb=0;mb<8;mb++) acc1[mb]=z4;
      #pragma unroll
      for(int kk=0;kk<4;kk++){
        bf16x8 b = *(const bf16x8*)(ldsY + swz(w*16+lm, kk*4+g));
        #pragma unroll
        for(int mb=0;mb<8;mb++){
          bf16x8 a = *(const bf16x8*)(ldsZ + swz(mb*16+lm, kk*4+g));
          acc1[mb] = __builtin_amdgcn_mfma_f32_16x16x32_bf16(a,b,acc1[mb],0,0,0);
        }
      }
      __syncthreads();                    // all waves done reading ldsZ; alias as E
      short* ldsE = ldsZ;
      const int jl = w*16 + lm;
      const float ybc = y128s[jl];
      #pragma unroll
      for(int mb=0;mb<8;mb++){
        bf16x4 pk;
        #pragma unroll
        for(int r=0;r<4;r++){
          float x = acc1[mb][r] + z128s[mb*16+4*g+r]*ybc;
          float e = jvalid ? __expf(x) : 0.f;
          pk[r]=f2bf(e);
        }
        int col = mb*16 + 4*g;
        int addr = jl*LSTR + (((col>>3) ^ ((jl>>3)&7))<<3) + (col&7);
        *(bf16x4*)(ldsE + addr) = pk;
      }
      #pragma unroll
      for(int kk=0;kk<4;kk++){
        bf16x8 b = *(const bf16x8*)(ldsE + swz(jl, kk*4+g));
        #pragma unroll
        for(int m=0;m<9;m++){
          const short* vp = Vbf + (size_t)(m*16+lm)*VS + i0 + kk*32 + 8*g;
          bf16x8 a = *(const bf16x8*)vp;
          acc2[m] = __builtin_amdgcn_mfma_f32_16x16x32_bf16(a,b,acc2[m],0,0,0);
        }
      }
    }
  }
  if constexpr(PASS==1){
    int jj = j0 + w*16 + lm;
    if(jj < N1){
      #pragma unroll
      for(int m=0;m<9;m++){
        #pragma unroll
        for(int r=0;r<4;r++){
          int dd = m*16 + 4*g + r;
          if(dd<D) atomicAdd(&Zn[(size_t)dd*N1+jj], INV_N*acc2[m][r]);
        }
      }
    }
  }
}

extern "C" void kernel_launch(void* const* d_in, const int* in_sizes, int n_in,
                              void* d_out, int out_size, void* d_ws, size_t ws_size,
                              hipStream_t stream){
  (void)in_sizes; (void)n_in; (void)out_size; (void)ws_size;
  const float* Zin=(const float*)d_in[0];
  const float* Pm =(const float*)d_in[1];
  const float* Qm =(const float*)d_in[2];
  float* out=(float*)d_out;
  char* base=(char*)d_ws;
  size_t off=0;
  auto alloc=[&](size_t b)->void*{ void* p=base+off; off=(off+b+255)&~(size_t)255; return p; };
  float* Z0 =(float*)alloc((size_t)D*N1*4);
  float* Z1 =(float*)alloc((size_t)D*N1*4);
  float* Yf =(float*)alloc((size_t)D*N1*4);
  float* PZ =(float*)alloc((size_t)D*N1*4);
  float* Wf =(float*)alloc((size_t)D*N1*4);
  float* S  =(float*)alloc((size_t)N1*4);
  short* Zbf=(short*)alloc((size_t)DK*ZS*2);
  short* Ybf=(short*)alloc((size_t)DK*ZS*2);
  short* Vbf=(short*)alloc((size_t)VROWS*VS*2);

  const float* Zc=Zin;
  for(int l=0;l<4;l++){
    float* Zn = (l==3)? out : ((l&1)? Z1:Z0);
    k_cast<<<dim3(1024),dim3(256),0,stream>>>(Zc,Zbf);
    k_small<<<dim3(33,17),dim3(256),0,stream>>>(Zc,Pm,Qm,Yf,Ybf,PZ);
    k_scan<<<dim3(33,129),dim3(256),0,stream>>>(PZ,Wf);
    hipMemsetAsync(S,0,(size_t)N1*4,stream);
    k_attn<0><<<dim3(129,8),dim3(256),0,stream>>>(Zbf,Ybf,Zc,Yf,S,(const short*)nullptr,(float*)nullptr);
    k_v<<<dim3(1024),dim3(256),0,stream>>>(Wf,S,Vbf);
    hipMemcpyAsync(Zn,Zc,(size_t)D*N1*4,hipMemcpyDeviceToDevice,stream);
    k_attn<1><<<dim3(129,8),dim3(256),0,stream>>>(Zbf,Ybf,Zc,Yf,S,Vbf,Zn);
    Zc=Zn;
  }
}

// Round 2
// 1518.583 us; speedup vs baseline: 1.4117x; 1.4117x over previous
//
#include <hip/hip_runtime.h>

#define D 129
#define N1 8193
#define NN 8192
#define INV_N (1.0f/8192.0f)
#define WSTR 8448        // fp32 row stride for PZ / W
#define VS 8192          // Vbf row stride (bf16)

typedef __attribute__((ext_vector_type(8))) short bf16x8;
typedef __attribute__((ext_vector_type(4))) float f32x4;

__device__ __forceinline__ short f2bf(float x){
  unsigned u = __float_as_uint(x);
  unsigned r = (u + 0x7fffu + ((u>>16)&1u)) >> 16;
  return (short)r;
}

__device__ __forceinline__ unsigned cvtpk(float a, float b){
  unsigned r; asm("v_cvt_pk_bf16_f32 %0, %1, %2" : "=v"(r) : "v"(a), "v"(b)); return r;
}

#define GLOAD_LDS16(gp, lp) __builtin_amdgcn_global_load_lds( \
    (const __attribute__((address_space(1))) void*)(gp),      \
    (__attribute__((address_space(3))) void*)(lp), 16, 0, 0)

// stage 128 rows x 256B from pre-swizzled [t][128] bf16 into linear LDS (32KB), 512 threads
__device__ __forceinline__ void stage128(const short* __restrict__ srcRow0, short* lds,
                                         int w, int lane){
  #pragma unroll
  for(int q=0;q<4;q++){
    int r = w*16 + q*4;
    const short* gp = srcRow0 + (size_t)(r + (lane>>4))*128 + ((lane&15)<<3);
    GLOAD_LDS16(gp, lds + r*128);
  }
}

// ---- transpose fp32 [d<128][N1] -> bf16 swizzled [t][128] (row t: group gb stored at gb^(t&7))
__global__ void k_tr(const float* __restrict__ src, short* __restrict__ dst, int tmax){
  __shared__ float tile[128][65];
  int t0 = blockIdx.x*64;
  int tid = threadIdx.x;
  for(int idx=tid; idx<128*64; idx+=256){
    int d = idx>>6, c = idx&63;
    int t = t0+c;
    tile[d][c] = (t<tmax) ? src[(size_t)d*N1 + t] : 0.f;
  }
  __syncthreads();
  int q = tid&3, tl = tid>>2;
  int t = t0 + tl;
  short* row = dst + (size_t)t*128;
  int s7 = t&7;
  #pragma unroll
  for(int gb2=0; gb2<4; gb2++){
    int gl = q*4+gb2;
    bf16x8 v;
    #pragma unroll
    for(int u=0;u<8;u++) v[u] = f2bf(tile[gl*8+u][tl]);
    *(bf16x8*)(row + ((gl^s7)<<3)) = v;
  }
}

// ---- Y = Q@Z, PZ = P@Z (fp32, K=129), 16 rows per y-block
__global__ void k_small(const float* __restrict__ Z, const float* __restrict__ P,
                        const float* __restrict__ Q, float* __restrict__ Yf,
                        float* __restrict__ PZ){
  __shared__ float qs[16][D], ps[16][D];
  int r0 = blockIdx.y*16;
  for(int i=threadIdx.x;i<16*D;i+=256){
    int rr=i/D, cc=i-rr*D;
    float qv=0.f, pv=0.f;
    if(r0+rr<D){ qv=Q[(r0+rr)*D+cc]; pv=P[(r0+rr)*D+cc]; }
    qs[rr][cc]=qv; ps[rr][cc]=pv;
  }
  __syncthreads();
  int t = blockIdx.x*256+threadIdx.x;
  if(t>=N1) return;
  float ay[16], ap[16];
  #pragma unroll
  for(int rr=0;rr<16;rr++){ ay[rr]=0.f; ap[rr]=0.f; }
  for(int k=0;k<D;k++){
    float z = Z[(size_t)k*N1+t];
    #pragma unroll
    for(int rr=0;rr<16;rr++){ ay[rr]=fmaf(qs[rr][k],z,ay[rr]); ap[rr]=fmaf(ps[rr][k],z,ap[rr]); }
  }
  #pragma unroll
  for(int rr=0;rr<16;rr++){
    int r=r0+rr;
    if(r<D){ Yf[(size_t)r*N1+t]=ay[rr]; PZ[(size_t)r*WSTR+t]=ap[rr]; }
  }
}

// ---- W[d,j] = PZ[d,j] + 0.9*W[d,j+1]; top of each 16-chunk via 256-tap (0.9^256~2e-12)
__global__ void k_scan(const float* __restrict__ PZ, float* __restrict__ W){
  __shared__ float s[2376];       // 2304 + skew
  int d = blockIdx.y;
  int base = blockIdx.x*2048;
  for(int i=threadIdx.x;i<2304;i+=128){
    int j = base+i;
    s[i + (i>>5)] = (j<NN)? PZ[(size_t)d*WSTR + j] : 0.f;
  }
  __syncthreads();
  int t = threadIdx.x;
  int jh = t*16+15;
  float acc = 0.f, f = 1.f;
  for(int k=0;k<256;k++){ int a = jh+k; acc = fmaf(f, s[a+(a>>5)], acc); f *= 0.9f; }
  float wv[16];
  wv[15] = acc;
  #pragma unroll
  for(int r=14;r>=0;r--){ int a = t*16+r; wv[r] = fmaf(0.9f, wv[r+1], s[a+(a>>5)]); }
  float* out = W + (size_t)d*WSTR + base + t*16;
  #pragma unroll
  for(int r=0;r<16;r+=4) *(f32x4*)(out+r) = (f32x4){wv[r],wv[r+1],wv[r+2],wv[r+3]};
}

// ---- V[d,i] = W[d,i]/S[i] (bf16, 144x8192), plus fp32 row d=128
__global__ void k_v(const float* __restrict__ W, const float* __restrict__ S,
                    short* __restrict__ V, float* __restrict__ V128f){
  int idx = blockIdx.x*256+threadIdx.x;
  if(idx >= 144*VS) return;
  int dd = idx>>13, ii = idx&8191;
  float v = 0.f;
  if(dd<D) v = W[(size_t)dd*WSTR + ii] / S[ii];
  V[idx] = f2bf(v);
  if(dd==128) V128f[ii] = v;
}

// ---- PASS 0: S[i] = sum_j exp(X[i,j]). Block: i-tile 128 (8 waves x 16), streams Y j-tiles.
__global__ __launch_bounds__(512) void k_attn0(
    const short* __restrict__ ZT, const short* __restrict__ YT,
    const float* __restrict__ z128, const float* __restrict__ y128, float* __restrict__ S){
  __shared__ short yt[2][128*128];
  const int tid=threadIdx.x, w=tid>>6, lane=tid&63, g=lane>>4, lm=lane&15;
  const int i0 = blockIdx.x*128;
  const int ime = i0 + w*16 + lm;
  bf16x8 az[4];
  {
    const short* zr = ZT + (size_t)ime*128;
    int s7 = ime&7;
    #pragma unroll
    for(int kk=0;kk<4;kk++) az[kk] = *(const bf16x8*)(zr + (((kk*4+g)^s7)<<3));
  }
  const f32x4 z4 = *(const f32x4*)(z128 + i0 + w*16 + 4*g);
  float ssum[4] = {0.f,0.f,0.f,0.f};
  const int jt0 = blockIdx.y*5;
  stage128(YT + (size_t)(jt0*128)*128, yt[0], w, lane);
  __syncthreads();
  for(int jt=0; jt<5; ++jt){
    const int j0 = (jt0+jt)*128;
    const short* yb = yt[jt&1];
    if(jt+1<5) stage128(YT + (size_t)(j0+128)*128, yt[(jt+1)&1], w, lane);
    #pragma unroll
    for(int jb=0; jb<8; ++jb){
      int jcol = j0 + jb*16 + lm;
      float ybv = (jcol<=NN) ? y128[jcol] : 0.f;
      f32x4 a1 = {0.f,0.f,0.f,0.f};
      #pragma unroll
      for(int kk=0;kk<4;kk++){
        int r = jb*16+lm;
        const short* bp = yb + r*128 + ((((kk*4+g)^(r&7)))<<3);
        a1 = __builtin_amdgcn_mfma_f32_16x16x32_bf16(az[kk], *(const bf16x8*)bp, a1, 0,0,0);
      }
      if(jcol<=NN){
        #pragma unroll
        for(int r4=0;r4<4;r4++) ssum[r4] += __expf(a1[r4] + z4[r4]*ybv);
      }
    }
    __syncthreads();
  }
  #pragma unroll
  for(int r4=0;r4<4;r4++){
    float v = ssum[r4];
    v += __shfl_xor(v,1); v += __shfl_xor(v,2); v += __shfl_xor(v,4); v += __shfl_xor(v,8);
    if(lm==0) atomicAdd(&S[i0 + w*16 + 4*g + r4], v);
  }
}

// ---- PASS 1: Zn[d,j] += INV_N * sum_i V[d,i]*exp(X[i,j]). Block: j-tile 128, streams Z i-tiles.
__global__ __launch_bounds__(512, 4) void k_attn1(
    const short* __restrict__ ZT, const short* __restrict__ YT,
    const float* __restrict__ z128, const float* __restrict__ y128,
    const short* __restrict__ Vbf, const float* __restrict__ V128f, float* __restrict__ Zn){
  __shared__ short zt[2][128*128];
  const int tid=threadIdx.x, w=tid>>6, lane=tid&63, g=lane>>4, lm=lane&15;
  const int j0 = blockIdx.x*128;
  const int jme = j0 + w*16 + lm;          // this lane's output column
  const bool jv = (jme <= NN);
  bf16x8 by[4];
  {
    const short* yr = YT + (size_t)jme*128;
    int s7 = jme&7;
    #pragma unroll
    for(int kk=0;kk<4;kk++) by[kk] = *(const bf16x8*)(yr + (((kk*4+g)^s7)<<3));
  }
  const float ybc = jv ? y128[jme] : 0.f;
  const int idx0 = ((((g&1)<<5) | lm))<<2;   // bpermute byte idx: source lane (2(g&1))*16+lm
  const int idx1 = idx0 + 64;                // source lane +16

  f32x4 acc2[8];
  #pragma unroll
  for(int m=0;m<8;m++) acc2[m]=(f32x4){0.f,0.f,0.f,0.f};
  float acc128 = 0.f;

  const int NT = 8;
  const int ibase = blockIdx.y * (NT*128);
  stage128(ZT + (size_t)ibase*128, zt[0], w, lane);
  __syncthreads();

  for(int it=0; it<NT; ++it){
    const int i0 = ibase + it*128;
    const short* zb = zt[it&1];
    if(it+1<NT) stage128(ZT + (size_t)(i0+128)*128, zt[(it+1)&1], w, lane);

    bf16x8 bfrag[4];
    #pragma unroll
    for(int h=0; h<2; ++h){
      f32x4 a1[4];
      #pragma unroll
      for(int mb=0;mb<4;mb++) a1[mb]=(f32x4){0.f,0.f,0.f,0.f};
      #pragma unroll
      for(int kk=0;kk<4;kk++){
        #pragma unroll
        for(int mb=0;mb<4;mb++){
          int r = (h*4+mb)*16 + lm;
          const short* ap = zb + r*128 + ((((kk*4+g)^(r&7)))<<3);
          a1[mb] = __builtin_amdgcn_mfma_f32_16x16x32_bf16(*(const bf16x8*)ap, by[kk], a1[mb], 0,0,0);
        }
      }
      #pragma unroll
      for(int q=0; q<2; ++q){
        unsigned res[2][4];
        #pragma unroll
        for(int par=0; par<2; ++par){
          int mb = q*2+par;
          int mbg = h*4 + mb;
          f32x4 zz = *(const f32x4*)(z128 + i0 + mbg*16 + 4*g);
          f32x4 v4 = *(const f32x4*)(V128f + i0 + mbg*16 + 4*g);
          float e0 = jv ? __expf(a1[mb][0] + zz[0]*ybc) : 0.f;
          float e1 = jv ? __expf(a1[mb][1] + zz[1]*ybc) : 0.f;
          float e2 = jv ? __expf(a1[mb][2] + zz[2]*ybc) : 0.f;
          float e3 = jv ? __expf(a1[mb][3] + zz[3]*ybc) : 0.f;
          acc128 = fmaf(v4[0], e0, acc128);
          acc128 = fmaf(v4[1], e1, acc128);
          acc128 = fmaf(v4[2], e2, acc128);
          acc128 = fmaf(v4[3], e3, acc128);
          unsigned p0 = cvtpk(e0,e1), p1 = cvtpk(e2,e3);
          res[par][0] = (unsigned)__builtin_amdgcn_ds_bpermute(idx0, (int)p0);
          res[par][1] = (unsigned)__builtin_amdgcn_ds_bpermute(idx0, (int)p1);
          res[par][2] = (unsigned)__builtin_amdgcn_ds_bpermute(idx1, (int)p0);
          res[par][3] = (unsigned)__builtin_amdgcn_ds_bpermute(idx1, (int)p1);
        }
        // receiving lane uses parity (g>>1): bfrag[2h+q] covers k=i-local [ (2h+q)*32 + g*8, +8 )
        union { unsigned u[4]; bf16x8 v; } bb;
        int sel = (g>>1);
        #pragma unroll
        for(int z=0; z<4; z++) bb.u[z] = sel ? res[1][z] : res[0][z];
        bfrag[h*2+q] = bb.v;
      }
    }
    // V @ E
    #pragma unroll
    for(int kk=0; kk<4; ++kk){
      #pragma unroll
      for(int m=0;m<8;m++){
        const short* vp = Vbf + (size_t)(m*16+lm)*VS + i0 + kk*32 + (g<<3);
        acc2[m] = __builtin_amdgcn_mfma_f32_16x16x32_bf16(*(const bf16x8*)vp, bfrag[kk], acc2[m], 0,0,0);
      }
    }
    __syncthreads();
  }

  acc128 += __shfl_xor(acc128, 16);
  acc128 += __shfl_xor(acc128, 32);
  if(jv){
    #pragma unroll
    for(int m=0;m<8;m++){
      #pragma unroll
      for(int r=0;r<4;r++){
        atomicAdd(&Zn[(size_t)(m*16+4*g+r)*N1 + jme], INV_N*acc2[m][r]);
      }
    }
    if(g==0) atomicAdd(&Zn[(size_t)128*N1 + jme], INV_N*acc128);
  }
}

extern "C" void kernel_launch(void* const* d_in, const int* in_sizes, int n_in,
                              void* d_out, int out_size, void* d_ws, size_t ws_size,
                              hipStream_t stream){
  (void)in_sizes; (void)n_in; (void)out_size; (void)ws_size;
  const float* Zin=(const float*)d_in[0];
  const float* Pm =(const float*)d_in[1];
  const float* Qm =(const float*)d_in[2];
  float* out=(float*)d_out;
  char* base=(char*)d_ws;
  size_t off=0;
  auto alloc=[&](size_t b)->void*{ void* p=base+off; off=(off+b+255)&~(size_t)255; return p; };
  float* Z0  =(float*)alloc((size_t)D*N1*4);
  float* Z1  =(float*)alloc((size_t)D*N1*4);
  float* Yf  =(float*)alloc((size_t)D*N1*4);
  float* PZ  =(float*)alloc((size_t)D*WSTR*4);
  float* Wf  =(float*)alloc((size_t)D*WSTR*4);
  float* S   =(float*)alloc((size_t)8448*4);
  short* ZT  =(short*)alloc((size_t)8192*128*2);
  short* YT  =(short*)alloc((size_t)8320*128*2);
  short* Vbf =(short*)alloc((size_t)144*VS*2);
  float* V128f=(float*)alloc((size_t)VS*4);

  const float* Zc=Zin;
  for(int l=0;l<4;l++){
    float* Zn = (l==3)? out : ((l&1)? Z1:Z0);
    k_small<<<dim3(33,9),dim3(256),0,stream>>>(Zc,Pm,Qm,Yf,PZ);
    k_tr<<<dim3(128),dim3(256),0,stream>>>(Zc,ZT,N1);
    k_tr<<<dim3(130),dim3(256),0,stream>>>(Yf,YT,N1);
    k_scan<<<dim3(4,D),dim3(128),0,stream>>>(PZ,Wf);
    hipMemsetAsync(S,0,(size_t)NN*4,stream);
    k_attn0<<<dim3(64,13),dim3(512),0,stream>>>(ZT,YT,Zc+(size_t)128*N1,Yf+(size_t)128*N1,S);
    k_v<<<dim3((144*VS)/256),dim3(256),0,stream>>>(Wf,S,Vbf,V128f);
    hipMemcpyAsync(Zn,Zc,(size_t)D*N1*4,hipMemcpyDeviceToDevice,stream);
    k_attn1<<<dim3(65,8),dim3(512),0,stream>>>(ZT,YT,Zc+(size_t)128*N1,Yf+(size_t)128*N1,Vbf,V128f,Zn);
    Zc=Zn;
  }
}

// Round 3
// 1202.736 us; speedup vs baseline: 1.7824x; 1.2626x over previous
//
#include <hip/hip_runtime.h>

#define D 129
#define N1 8193
#define NN 8192
#define INV_N (1.0f/8192.0f)
#define WSTR 8448        // fp32 row stride for PZ / W
#define KP 160           // padded K (129 -> 160, cols 129..159 zero)
#define TROWS 8448       // rows in ZT/YT (multiple of 256)
#define PSTR 8320        // part row stride (fp32)

typedef __attribute__((ext_vector_type(8))) short bf16x8;
typedef __attribute__((ext_vector_type(4))) float f32x4;

__device__ __forceinline__ short f2bf(float x){
  unsigned u = __float_as_uint(x);
  unsigned r = (u + 0x7fffu + ((u>>16)&1u)) >> 16;
  return (short)r;
}

#define GLOAD_LDS16(gp, lp) __builtin_amdgcn_global_load_lds( \
    (const __attribute__((address_space(1))) void*)(gp),      \
    (__attribute__((address_space(3))) void*)(lp), 16, 0, 0)

// ---- transpose fp32 [129][N1] -> bf16 swizzled [t][160]; col 128 = row128, 129..159 = 0
__global__ void k_tr(const float* __restrict__ src, short* __restrict__ dst, int tmax){
  __shared__ float tile[129][65];
  int t0 = blockIdx.x*64, tid = threadIdx.x;
  for(int idx=tid; idx<129*64; idx+=256){
    int d = idx>>6, c = idx&63;
    tile[d][c] = (t0+c < tmax)? src[(size_t)d*N1 + t0+c] : 0.f;
  }
  __syncthreads();
  int q = tid&3, tl = tid>>2;
  int t = t0 + tl;
  short* row = dst + (size_t)t*KP;
  int s7 = t&7;
  #pragma unroll
  for(int g5=0; g5<5; g5++){
    int gi = q*5 + g5;
    bf16x8 v;
    if(gi < 16){
      #pragma unroll
      for(int u=0;u<8;u++) v[u] = f2bf(tile[gi*8+u][tl]);
      *(bf16x8*)(row + ((gi^s7)<<3)) = v;
    } else if(gi == 16){
      v[0] = f2bf(tile[128][tl]);
      #pragma unroll
      for(int u=1;u<8;u++) v[u] = 0;
      *(bf16x8*)(row + (16<<3)) = v;
    } else {
      #pragma unroll
      for(int u=0;u<8;u++) v[u] = 0;
      *(bf16x8*)(row + (gi<<3)) = v;
    }
  }
}

// ---- Y = Q@Z, PZ = P@Z (fp32, K=129)
__global__ void k_small(const float* __restrict__ Z, const float* __restrict__ P,
                        const float* __restrict__ Q, float* __restrict__ Yf,
                        float* __restrict__ PZ){
  __shared__ float qs[16][D], ps[16][D];
  int r0 = blockIdx.y*16;
  for(int i=threadIdx.x;i<16*D;i+=256){
    int rr=i/D, cc=i-rr*D;
    float qv=0.f, pv=0.f;
    if(r0+rr<D){ qv=Q[(r0+rr)*D+cc]; pv=P[(r0+rr)*D+cc]; }
    qs[rr][cc]=qv; ps[rr][cc]=pv;
  }
  __syncthreads();
  int t = blockIdx.x*256+threadIdx.x;
  if(t>=N1) return;
  float ay[16], ap[16];
  #pragma unroll
  for(int rr=0;rr<16;rr++){ ay[rr]=0.f; ap[rr]=0.f; }
  for(int k=0;k<D;k++){
    float z = Z[(size_t)k*N1+t];
    #pragma unroll
    for(int rr=0;rr<16;rr++){ ay[rr]=fmaf(qs[rr][k],z,ay[rr]); ap[rr]=fmaf(ps[rr][k],z,ap[rr]); }
  }
  #pragma unroll
  for(int rr=0;rr<16;rr++){
    int r=r0+rr;
    if(r<D){ Yf[(size_t)r*N1+t]=ay[rr]; PZ[(size_t)r*WSTR+t]=ap[rr]; }
  }
}

// ---- W[d,j] = PZ[d,j] + 0.9*W[d,j+1] (256-tap truncation at 16-chunk heads)
__global__ void k_scan(const float* __restrict__ PZ, float* __restrict__ W){
  __shared__ float s[2376];
  int d = blockIdx.y;
  int base = blockIdx.x*2048;
  for(int i=threadIdx.x;i<2304;i+=128){
    int j = base+i;
    s[i + (i>>5)] = (j<NN)? PZ[(size_t)d*WSTR + j] : 0.f;
  }
  __syncthreads();
  int t = threadIdx.x;
  int jh = t*16+15;
  float acc = 0.f, f = 1.f;
  for(int k=0;k<256;k++){ int a = jh+k; acc = fmaf(f, s[a+(a>>5)], acc); f *= 0.9f; }
  float wv[16];
  wv[15] = acc;
  #pragma unroll
  for(int r=14;r>=0;r--){ int a = t*16+r; wv[r] = fmaf(0.9f, wv[r+1], s[a+(a>>5)]); }
  float* out = W + (size_t)d*WSTR + base + t*16;
  #pragma unroll
  for(int r=0;r<16;r+=4) *(f32x4*)(out+r) = (f32x4){wv[r],wv[r+1],wv[r+2],wv[r+3]};
}

// ---- V tiles: Vt[it][144 d][128 i] bf16, XOR-swizzled rows, rows 129..143 zero
__global__ void k_v(const float* __restrict__ W, const float* __restrict__ S,
                    short* __restrict__ Vt, int tile0){
  int idx = blockIdx.x*256+threadIdx.x;
  int l = idx/18432, rem = idx - l*18432;
  int d = rem>>7, ci = rem&127;
  int it = tile0 + l;
  int i = it*128 + ci;
  float v = (d<=128)? W[(size_t)d*WSTR + i]/S[i] : 0.f;
  int gs = (ci>>3) ^ (d&7);
  Vt[(size_t)it*18432 + (d<<7) + gs*8 + (ci&7)] = f2bf(v);
}

// ---- pass0: per block one [256 j][128 i] tile of X^T; E=exp stored bf16; S row-sums
__global__ __launch_bounds__(512,4) void k_qke(
    const short* __restrict__ ZT, const short* __restrict__ YT,
    short* __restrict__ Ebuf, float* __restrict__ S, int tile0, int ITC){
  __shared__ short zt[128*KP];
  __shared__ float sred[128];
  const int tid=threadIdx.x, w=tid>>6, lane=tid&63, g=lane>>4, lm=lane&15;
  const int itl = blockIdx.y, it = tile0 + itl;
  const int jtb = blockIdx.x;           // j0 = jtb*256
  const int sx = lm&7;

  // stage Z tile (contiguous 40960B)
  const short* ztg = ZT + (size_t)it*(128*KP);
  #pragma unroll
  for(int q=0;q<5;q++){
    int off = (q*512 + tid)*8;
    GLOAD_LDS16(ztg + off, zt + off);
  }
  if(tid<128) sred[tid]=0.f;

  // A-frags from global YT (rows = this wave's 32 j-rows)
  bf16x8 a[2][5];
  #pragma unroll
  for(int p=0;p<2;p++){
    int jr = jtb*256 + w*32 + p*16 + lm;
    const short* rp = YT + (size_t)jr*KP;
    #pragma unroll
    for(int kk=0;kk<4;kk++) a[p][kk] = *(const bf16x8*)(rp + (((kk*4+g)^sx)<<3));
    a[p][4] = *(const bf16x8*)(rp + ((16+g)<<3));
  }
  __syncthreads();

  #pragma unroll
  for(int ib=0;ib<8;ib++){
    const short* zp = zt + (ib*16+lm)*KP;
    f32x4 acc0 = {0.f,0.f,0.f,0.f}, acc1 = {0.f,0.f,0.f,0.f};
    #pragma unroll
    for(int kk=0;kk<4;kk++){
      bf16x8 b = *(const bf16x8*)(zp + (((kk*4+g)^sx)<<3));
      acc0 = __builtin_amdgcn_mfma_f32_16x16x32_bf16(a[0][kk], b, acc0, 0,0,0);
      acc1 = __builtin_amdgcn_mfma_f32_16x16x32_bf16(a[1][kk], b, acc1, 0,0,0);
    }
    {
      bf16x8 b = *(const bf16x8*)(zp + ((16+g)<<3));
      acc0 = __builtin_amdgcn_mfma_f32_16x16x32_bf16(a[0][4], b, acc0, 0,0,0);
      acc1 = __builtin_amdgcn_mfma_f32_16x16x32_bf16(a[1][4], b, acc1, 0,0,0);
    }
    float ps = 0.f;
    #pragma unroll
    for(int p=0;p<2;p++){
      f32x4 av = p? acc1 : acc0;
      int jb_ = jtb*256 + w*32 + p*16 + g*4;
      #pragma unroll
      for(int r=0;r<4;r++){
        int j = jb_ + r;
        float e = (j<=NN)? __expf(av[r]) : 0.f;
        ps += e;
        int tj = j>>7, erow = j&127;
        short* ep = Ebuf + ((size_t)tj*ITC + itl)*16384;
        int gs = (ib*2 + (lm>>3)) ^ (erow&7);
        ep[erow*128 + gs*8 + (lm&7)] = f2bf(e);
      }
    }
    ps += __shfl_xor(ps,16); ps += __shfl_xor(ps,32);
    if(g==0) atomicAdd(&sred[ib*16+lm], ps);
  }
  __syncthreads();
  if(tid<128) atomicAdd(&S[it*128+tid], sred[tid]);
}

// ---- pass1: out-partial[ksg][144 d][128 j] = V @ E over this task's K range. No LDS.
__global__ __launch_bounds__(256,4) void k_pv(
    const short* __restrict__ Ebuf, const short* __restrict__ Vt,
    float* __restrict__ part, int ITC, int tile0, int ks_base, int nT){
  const int tid=threadIdx.x, w=tid>>6, lane=tid&63, g=lane>>4, lm=lane&15;
  const int jt = blockIdx.x;
  const int ksg = ks_base + blockIdx.y;
  const int jr0 = w*32 + lm, jr1 = jr0 + 16;
  const int sx = lm&7;
  f32x4 acc[2][9];
  #pragma unroll
  for(int p=0;p<2;p++)
    #pragma unroll
    for(int m=0;m<9;m++) acc[p][m] = (f32x4){0.f,0.f,0.f,0.f};

  for(int t=0;t<nT;t++){
    int git = ksg*nT + t;
    const short* et = Ebuf + ((size_t)jt*ITC + (git - tile0))*16384;
    const short* vt = Vt + (size_t)git*18432;
    #pragma unroll
    for(int kk=0;kk<4;kk++){
      int go = ((kk*4+g)^sx)<<3;
      bf16x8 b0 = *(const bf16x8*)(et + jr0*128 + go);
      bf16x8 b1 = *(const bf16x8*)(et + jr1*128 + go);
      #pragma unroll
      for(int m=0;m<9;m++){
        bf16x8 av = *(const bf16x8*)(vt + ((m*16+lm)<<7) + go);
        acc[0][m] = __builtin_amdgcn_mfma_f32_16x16x32_bf16(av, b0, acc[0][m], 0,0,0);
        acc[1][m] = __builtin_amdgcn_mfma_f32_16x16x32_bf16(av, b1, acc[1][m], 0,0,0);
      }
    }
  }
  float* pb = part + (size_t)ksg*144*PSTR;
  #pragma unroll
  for(int p=0;p<2;p++){
    int j = jt*128 + w*32 + p*16 + lm;
    if(j<=NN){
      #pragma unroll
      for(int m=0;m<9;m++){
        #pragma unroll
        for(int r=0;r<4;r++)
          pb[(size_t)(m*16+g*4+r)*PSTR + j] = acc[p][m][r];
      }
    }
  }
}

// ---- out = Zc + INV_N * sum_ks part[ks]
__global__ void k_out(const float* __restrict__ Zc, const float* __restrict__ part,
                      float* __restrict__ out, int st){
  int idx = blockIdx.x*256+threadIdx.x;
  if(idx >= 129*2049) return;
  int d = idx/2049, jq = idx - d*2049;
  int j0 = jq*4;
  float s0=0.f,s1=0.f,s2=0.f,s3=0.f;
  for(int ks=0;ks<st;ks++){
    f32x4 v = *(const f32x4*)(part + (size_t)ks*144*PSTR + (size_t)d*PSTR + j0);
    s0+=v[0]; s1+=v[1]; s2+=v[2]; s3+=v[3];
  }
  const float* zr = Zc + (size_t)d*N1;
  float* orow = out + (size_t)d*N1;
  float sv[4] = {s0,s1,s2,s3};
  #pragma unroll
  for(int u=0;u<4;u++){
    int j = j0+u;
    if(j < N1) orow[j] = zr[j] + INV_N*sv[u];
  }
}

extern "C" void kernel_launch(void* const* d_in, const int* in_sizes, int n_in,
                              void* d_out, int out_size, void* d_ws, size_t ws_size,
                              hipStream_t stream){
  (void)in_sizes; (void)n_in; (void)out_size;
  const float* Zin=(const float*)d_in[0];
  const float* Pm =(const float*)d_in[1];
  const float* Qm =(const float*)d_in[2];
  float* out=(float*)d_out;

  // pick (chunks c, K-splits st) so workspace fits
  const size_t fixed = 3*(size_t)D*N1*4 + 2*(size_t)D*WSTR*4 + (size_t)WSTR*4
                     + 2*(size_t)TROWS*KP*2 + (size_t)64*18432*2 + 8*4096;
  int c=8, st=4;
  {
    const int cs[6] = {1,2,4,8,8,8};
    const int ss[6] = {16,16,16,16,8,4};
    for(int k=0;k<6;k++){
      size_t need = fixed + (size_t)ss[k]*144*PSTR*4 + (size_t)66*(64/cs[k])*16384*2;
      if(need <= ws_size){ c=cs[k]; st=ss[k]; break; }
    }
  }
  const int ITC = 64/c, nT = 64/st, ksPC = st/c;

  char* base=(char*)d_ws;
  size_t off=0;
  auto alloc=[&](size_t b)->void*{ void* p=base+off; off=(off+b+255)&~(size_t)255; return p; };
  float* Z0  =(float*)alloc((size_t)D*N1*4);
  float* Z1  =(float*)alloc((size_t)D*N1*4);
  float* Yf  =(float*)alloc((size_t)D*N1*4);
  float* PZ  =(float*)alloc((size_t)D*WSTR*4);
  float* Wf  =(float*)alloc((size_t)D*WSTR*4);
  float* S   =(float*)alloc((size_t)WSTR*4);
  short* ZT  =(short*)alloc((size_t)TROWS*KP*2);
  short* YT  =(short*)alloc((size_t)TROWS*KP*2);
  short* Vt  =(short*)alloc((size_t)64*18432*2);
  float* part=(float*)alloc((size_t)st*144*PSTR*4);
  short* Ebuf=(short*)alloc((size_t)66*ITC*16384*2);

  const float* Zc=Zin;
  for(int l=0;l<4;l++){
    float* Zn = (l==3)? out : ((l&1)? Z1:Z0);
    k_small<<<dim3(33,9),dim3(256),0,stream>>>(Zc,Pm,Qm,Yf,PZ);
    k_tr<<<dim3(132),dim3(256),0,stream>>>(Zc,ZT,N1);
    k_tr<<<dim3(132),dim3(256),0,stream>>>(Yf,YT,N1);
    k_scan<<<dim3(4,D),dim3(128),0,stream>>>(PZ,Wf);
    hipMemsetAsync(S,0,(size_t)NN*4,stream);
    for(int ch=0; ch<c; ch++){
      int tile0 = ch*ITC;
      k_qke<<<dim3(33,ITC),dim3(512),0,stream>>>(ZT,YT,Ebuf,S,tile0,ITC);
      k_v<<<dim3(ITC*72),dim3(256),0,stream>>>(Wf,S,Vt,tile0);
      k_pv<<<dim3(65,ksPC),dim3(256),0,stream>>>(Ebuf,Vt,part,ITC,tile0,ch*ksPC,nT);
    }
    k_out<<<dim3(1033),dim3(256),0,stream>>>(Zc,part,Zn,st);
    Zc=Zn;
  }
}

// Round 4
// 859.519 us; speedup vs baseline: 2.4942x; 1.3993x over previous
//
#include <hip/hip_runtime.h>

#define D 129
#define N1 8193
#define NN 8192
#define INV_N (1.0f/8192.0f)
#define WSTR 8448        // fp32 row stride for PZ / W
#define KP 160           // padded K (129 -> 160, cols 129..159 zero)
#define TROWS 8448       // rows in ZT/YT (multiple of 256)
#define PSTR 8320        // part row stride (fp32)

typedef __attribute__((ext_vector_type(8))) short bf16x8;
typedef __attribute__((ext_vector_type(4))) float f32x4;

__device__ __forceinline__ short f2bf(float x){
  unsigned u = __float_as_uint(x);
  unsigned r = (u + 0x7fffu + ((u>>16)&1u)) >> 16;
  return (short)r;
}

#define GLOAD_LDS16(gp, lp) __builtin_amdgcn_global_load_lds( \
    (const __attribute__((address_space(1))) void*)(gp),      \
    (__attribute__((address_space(3))) void*)(lp), 16, 0, 0)

// ---- transpose fp32 [129][N1] -> bf16 swizzled [t][160]; col 128 = row128, 129..159 = 0
__global__ void k_tr(const float* __restrict__ src, short* __restrict__ dst, int tmax){
  __shared__ float tile[129][65];
  int t0 = blockIdx.x*64, tid = threadIdx.x;
  for(int idx=tid; idx<129*64; idx+=256){
    int d = idx>>6, c = idx&63;
    tile[d][c] = (t0+c < tmax)? src[(size_t)d*N1 + t0+c] : 0.f;
  }
  __syncthreads();
  int q = tid&3, tl = tid>>2;
  int t = t0 + tl;
  short* row = dst + (size_t)t*KP;
  int s7 = t&7;
  #pragma unroll
  for(int g5=0; g5<5; g5++){
    int gi = q*5 + g5;
    bf16x8 v;
    if(gi < 16){
      #pragma unroll
      for(int u=0;u<8;u++) v[u] = f2bf(tile[gi*8+u][tl]);
      *(bf16x8*)(row + ((gi^s7)<<3)) = v;
    } else if(gi == 16){
      v[0] = f2bf(tile[128][tl]);
      #pragma unroll
      for(int u=1;u<8;u++) v[u] = 0;
      *(bf16x8*)(row + (16<<3)) = v;
    } else {
      #pragma unroll
      for(int u=0;u<8;u++) v[u] = 0;
      *(bf16x8*)(row + (gi<<3)) = v;
    }
  }
}

// ---- Y = Q@Z, PZ = P@Z (fp32, K=129)
__global__ void k_small(const float* __restrict__ Z, const float* __restrict__ P,
                        const float* __restrict__ Q, float* __restrict__ Yf,
                        float* __restrict__ PZ){
  __shared__ float qs[16][D], ps[16][D];
  int r0 = blockIdx.y*16;
  for(int i=threadIdx.x;i<16*D;i+=256){
    int rr=i/D, cc=i-rr*D;
    float qv=0.f, pv=0.f;
    if(r0+rr<D){ qv=Q[(r0+rr)*D+cc]; pv=P[(r0+rr)*D+cc]; }
    qs[rr][cc]=qv; ps[rr][cc]=pv;
  }
  __syncthreads();
  int t = blockIdx.x*256+threadIdx.x;
  if(t>=N1) return;
  float ay[16], ap[16];
  #pragma unroll
  for(int rr=0;rr<16;rr++){ ay[rr]=0.f; ap[rr]=0.f; }
  for(int k=0;k<D;k++){
    float z = Z[(size_t)k*N1+t];
    #pragma unroll
    for(int rr=0;rr<16;rr++){ ay[rr]=fmaf(qs[rr][k],z,ay[rr]); ap[rr]=fmaf(ps[rr][k],z,ap[rr]); }
  }
  #pragma unroll
  for(int rr=0;rr<16;rr++){
    int r=r0+rr;
    if(r<D){ Yf[(size_t)r*N1+t]=ay[rr]; PZ[(size_t)r*WSTR+t]=ap[rr]; }
  }
}

// ---- W[d,j] = PZ[d,j] + 0.9*W[d,j+1] (256-tap truncation at 16-chunk heads)
__global__ void k_scan(const float* __restrict__ PZ, float* __restrict__ W){
  __shared__ float s[2376];
  int d = blockIdx.y;
  int base = blockIdx.x*2048;
  for(int i=threadIdx.x;i<2304;i+=128){
    int j = base+i;
    s[i + (i>>5)] = (j<NN)? PZ[(size_t)d*WSTR + j] : 0.f;
  }
  __syncthreads();
  int t = threadIdx.x;
  int jh = t*16+15;
  float acc = 0.f, f = 1.f;
  for(int k=0;k<256;k++){ int a = jh+k; acc = fmaf(f, s[a+(a>>5)], acc); f *= 0.9f; }
  float wv[16];
  wv[15] = acc;
  #pragma unroll
  for(int r=14;r>=0;r--){ int a = t*16+r; wv[r] = fmaf(0.9f, wv[r+1], s[a+(a>>5)]); }
  float* out = W + (size_t)d*WSTR + base + t*16;
  #pragma unroll
  for(int r=0;r<16;r+=4) *(f32x4*)(out+r) = (f32x4){wv[r],wv[r+1],wv[r+2],wv[r+3]};
}

// ---- V tiles: Vt[it][144 d][128 i] bf16, XOR-swizzled rows, rows 129..143 zero
__global__ void k_v(const float* __restrict__ W, const float* __restrict__ S,
                    short* __restrict__ Vt, int tile0){
  int idx = blockIdx.x*256+threadIdx.x;
  int l = idx/18432, rem = idx - l*18432;
  int d = rem>>7, ci = rem&127;
  int it = tile0 + l;
  int i = it*128 + ci;
  float v = (d<=128)? W[(size_t)d*WSTR + i]/S[i] : 0.f;
  int gs = (ci>>3) ^ (d&7);
  Vt[(size_t)it*18432 + (d<<7) + gs*8 + (ci&7)] = f2bf(v);
}

// ---- pass0: per block one [256 j][128 i] tile of X^T; E=exp stored bf16; S row-sums
__global__ __launch_bounds__(512,4) void k_qke(
    const short* __restrict__ ZT, const short* __restrict__ YT,
    short* __restrict__ Ebuf, float* __restrict__ S, int tile0, int ITC){
  __shared__ short zt[128*KP];
  __shared__ float sred[128];
  const int tid=threadIdx.x, w=tid>>6, lane=tid&63, g=lane>>4, lm=lane&15;
  const int itl = blockIdx.y, it = tile0 + itl;
  const int jtb = blockIdx.x;           // j0 = jtb*256
  const int sx = lm&7;

  // stage Z tile (contiguous 40960B)
  const short* ztg = ZT + (size_t)it*(128*KP);
  #pragma unroll
  for(int q=0;q<5;q++){
    int off = (q*512 + tid)*8;
    GLOAD_LDS16(ztg + off, zt + off);
  }
  if(tid<128) sred[tid]=0.f;

  // A-frags from global YT (rows = this wave's 32 j-rows)
  bf16x8 a[2][5];
  #pragma unroll
  for(int p=0;p<2;p++){
    int jr = jtb*256 + w*32 + p*16 + lm;
    const short* rp = YT + (size_t)jr*KP;
    #pragma unroll
    for(int kk=0;kk<4;kk++) a[p][kk] = *(const bf16x8*)(rp + (((kk*4+g)^sx)<<3));
    a[p][4] = *(const bf16x8*)(rp + ((16+g)<<3));
  }
  __syncthreads();

  #pragma unroll
  for(int ib=0;ib<8;ib++){
    const short* zp = zt + (ib*16+lm)*KP;
    f32x4 acc0 = {0.f,0.f,0.f,0.f}, acc1 = {0.f,0.f,0.f,0.f};
    #pragma unroll
    for(int kk=0;kk<4;kk++){
      bf16x8 b = *(const bf16x8*)(zp + (((kk*4+g)^sx)<<3));
      acc0 = __builtin_amdgcn_mfma_f32_16x16x32_bf16(a[0][kk], b, acc0, 0,0,0);
      acc1 = __builtin_amdgcn_mfma_f32_16x16x32_bf16(a[1][kk], b, acc1, 0,0,0);
    }
    {
      bf16x8 b = *(const bf16x8*)(zp + ((16+g)<<3));
      acc0 = __builtin_amdgcn_mfma_f32_16x16x32_bf16(a[0][4], b, acc0, 0,0,0);
      acc1 = __builtin_amdgcn_mfma_f32_16x16x32_bf16(a[1][4], b, acc1, 0,0,0);
    }
    float ps = 0.f;
    #pragma unroll
    for(int p=0;p<2;p++){
      f32x4 av = p? acc1 : acc0;
      int jb_ = jtb*256 + w*32 + p*16 + g*4;
      #pragma unroll
      for(int r=0;r<4;r++){
        int j = jb_ + r;
        float e = (j<=NN)? __expf(av[r]) : 0.f;
        ps += e;
        int tj = j>>7, erow = j&127;
        short* ep = Ebuf + ((size_t)tj*ITC + itl)*16384;
        int gs = (ib*2 + (lm>>3)) ^ (erow&7);
        ep[erow*128 + gs*8 + (lm&7)] = f2bf(e);
      }
    }
    ps += __shfl_xor(ps,16); ps += __shfl_xor(ps,32);
    if(g==0) atomicAdd(&sred[ib*16+lm], ps);
  }
  __syncthreads();
  if(tid<128) atomicAdd(&S[it*128+tid], sred[tid]);
}

// ---- pass1: part[ks][144 d][128 j] = V @ E over nT i-tiles. LDS-staged, double-buffered.
__global__ __launch_bounds__(512) void k_pv(
    const short* __restrict__ Ebuf, const short* __restrict__ Vt,
    float* __restrict__ part, int ITC, int tile0, int ks_base, int nT){
  __shared__ short lds[2][34816];     // [buf]: E tile 16384 shorts + V tile 18432 shorts
  const int tid=threadIdx.x, w=tid>>6, lane=tid&63, g=lane>>4, lm=lane&15;
  const int jt = blockIdx.x;
  const int ks = ks_base + blockIdx.y;
  const int t0l = blockIdx.y*nT;      // local tile index base within this chunk
  const int sx = lm&7;

  f32x4 acc[9];
  #pragma unroll
  for(int m=0;m<9;m++) acc[m] = (f32x4){0.f,0.f,0.f,0.f};

  auto stage = [&](int buf, int tl){
    const short* eg = Ebuf + ((size_t)jt*ITC + tl)*16384;
    short* eb = &lds[buf][0];
    #pragma unroll
    for(int q=0;q<4;q++){
      int off = (q*512 + tid)*8;
      GLOAD_LDS16(eg + off, eb + off);
    }
    const short* vg = Vt + (size_t)(tile0 + tl)*18432;
    short* vb = &lds[buf][16384];
    #pragma unroll
    for(int q=0;q<5;q++){
      int off = (q*512 + tid)*8;
      if(q<4 || tid<256) GLOAD_LDS16(vg + off, vb + off);
    }
  };

  stage(0, t0l);
  __syncthreads();

  for(int t=0; t<nT; ++t){
    if(t+1<nT) stage((t+1)&1, t0l+t+1);
    const short* eb = &lds[t&1][0];
    const short* vb = &lds[t&1][16384];
    const short* ep = eb + (w*16+lm)*128;
    #pragma unroll
    for(int kk=0;kk<4;kk++){
      int go = ((kk*4+g)^sx)<<3;
      bf16x8 b = *(const bf16x8*)(ep + go);
      #pragma unroll
      for(int m=0;m<9;m++){
        bf16x8 av = *(const bf16x8*)(vb + ((m*16+lm)<<7) + go);
        acc[m] = __builtin_amdgcn_mfma_f32_16x16x32_bf16(av, b, acc[m], 0,0,0);
      }
    }
    __syncthreads();
  }

  float* pb = part + (size_t)ks*144*PSTR;
  const int j = jt*128 + w*16 + lm;
  #pragma unroll
  for(int m=0;m<9;m++){
    #pragma unroll
    for(int r=0;r<4;r++)
      pb[(size_t)(m*16+g*4+r)*PSTR + j] = acc[m][r];
  }
}

// ---- out = Zc + INV_N * sum_ks part[ks]
__global__ void k_out(const float* __restrict__ Zc, const float* __restrict__ part,
                      float* __restrict__ out, int st){
  int idx = blockIdx.x*256+threadIdx.x;
  if(idx >= 129*2049) return;
  int d = idx/2049, jq = idx - d*2049;
  int j0 = jq*4;
  float s0=0.f,s1=0.f,s2=0.f,s3=0.f;
  for(int ks=0;ks<st;ks++){
    f32x4 v = *(const f32x4*)(part + (size_t)ks*144*PSTR + (size_t)d*PSTR + j0);
    s0+=v[0]; s1+=v[1]; s2+=v[2]; s3+=v[3];
  }
  const float* zr = Zc + (size_t)d*N1;
  float* orow = out + (size_t)d*N1;
  float sv[4] = {s0,s1,s2,s3};
  #pragma unroll
  for(int u=0;u<4;u++){
    int j = j0+u;
    if(j < N1) orow[j] = zr[j] + INV_N*sv[u];
  }
}

extern "C" void kernel_launch(void* const* d_in, const int* in_sizes, int n_in,
                              void* d_out, int out_size, void* d_ws, size_t ws_size,
                              hipStream_t stream){
  (void)in_sizes; (void)n_in; (void)out_size;
  const float* Zin=(const float*)d_in[0];
  const float* Pm =(const float*)d_in[1];
  const float* Qm =(const float*)d_in[2];
  float* out=(float*)d_out;

  // config ladder: c chunks of i-tiles; k_pv grid y = ksPC stripes per chunk; st = c*ksPC
  const size_t fixed = 3*(size_t)D*N1*4 + 2*(size_t)D*WSTR*4 + (size_t)WSTR*4
                     + 2*(size_t)TROWS*KP*2 + (size_t)64*18432*2 + 16*4096;
  int c=8, ksPC=1;
  {
    const int cs[4] = {1,2,4,8};
    const int kp[4] = {4,2,1,1};
    for(int k=0;k<4;k++){
      int stc = cs[k]*kp[k];
      size_t need = fixed + (size_t)stc*144*PSTR*4 + (size_t)66*(64/cs[k])*16384*2;
      if(need <= ws_size){ c=cs[k]; ksPC=kp[k]; break; }
    }
  }
  const int ITC = 64/c, nT = ITC/ksPC, st = c*ksPC;

  char* base=(char*)d_ws;
  size_t off=0;
  auto alloc=[&](size_t b)->void*{ void* p=base+off; off=(off+b+255)&~(size_t)255; return p; };
  float* Z0  =(float*)alloc((size_t)D*N1*4);
  float* Z1  =(float*)alloc((size_t)D*N1*4);
  float* Yf  =(float*)alloc((size_t)D*N1*4);
  float* PZ  =(float*)alloc((size_t)D*WSTR*4);
  float* Wf  =(float*)alloc((size_t)D*WSTR*4);
  float* S   =(float*)alloc((size_t)WSTR*4);
  short* ZT  =(short*)alloc((size_t)TROWS*KP*2);
  short* YT  =(short*)alloc((size_t)TROWS*KP*2);
  short* Vt  =(short*)alloc((size_t)64*18432*2);
  float* part=(float*)alloc((size_t)st*144*PSTR*4);
  short* Ebuf=(short*)alloc((size_t)66*ITC*16384*2);

  const float* Zc=Zin;
  for(int l=0;l<4;l++){
    float* Zn = (l==3)? out : ((l&1)? Z1:Z0);
    k_small<<<dim3(33,9),dim3(256),0,stream>>>(Zc,Pm,Qm,Yf,PZ);
    k_tr<<<dim3(132),dim3(256),0,stream>>>(Zc,ZT,N1);
    k_tr<<<dim3(132),dim3(256),0,stream>>>(Yf,YT,N1);
    k_scan<<<dim3(4,D),dim3(128),0,stream>>>(PZ,Wf);
    hipMemsetAsync(S,0,(size_t)NN*4,stream);
    for(int ch=0; ch<c; ch++){
      int tile0 = ch*ITC;
      k_qke<<<dim3(33,ITC),dim3(512),0,stream>>>(ZT,YT,Ebuf,S,tile0,ITC);
      k_v<<<dim3(ITC*72),dim3(256),0,stream>>>(Wf,S,Vt,tile0);
      k_pv<<<dim3(65,ksPC),dim3(512),0,stream>>>(Ebuf,Vt,part,ITC,tile0,ch*ksPC,nT);
    }
    k_out<<<dim3(1033),dim3(256),0,stream>>>(Zc,part,Zn,st);
    Zc=Zn;
  }
}